// Round 13
// baseline (315.246 us; speedup 1.0000x reference)
//
#include <hip/hip_runtime.h>
#include <hip/hip_bf16.h>

#define NB 1024
#define NH 256
#define EMB 128
#define TWOD 256
#define HID 256
#define ROWS 128            // history rows per block
#define BPB 2               // blocks per batch element
#define NBLK (NB * BPB)

typedef __attribute__((ext_vector_type(4))) float f32x4;
typedef __attribute__((ext_vector_type(8))) short bf16x8;

__device__ __forceinline__ unsigned short f2bf(float f) {
  union { float f; unsigned u; } v; v.f = f;
  unsigned u = v.u;
  unsigned r = (u + 0x7fffu + ((u >> 16) & 1u)) >> 16;
  return (unsigned short)r;
}

// W1 [d=256][n=256] fp32 -> W1T [n][d] bf16, coalesced both sides via LDS
// tile transpose (16 blocks of 64x64 tiles; R12's version scattered 2B writes).
__global__ __launch_bounds__(256) void prep_w1t(const float* __restrict__ W1,
                                                unsigned short* __restrict__ W1T) {
  const int bx = blockIdx.x & 3;        // d-tile
  const int by = blockIdx.x >> 2;       // n-tile
  __shared__ float tile[64][65];        // +1 pad: conflict-free transpose read
  const int tr = threadIdx.x >> 6;      // 0..3
  const int tc = threadIdx.x & 63;      // 0..63
  #pragma unroll
  for (int i = 0; i < 16; ++i) {
    const int d = bx * 64 + i * 4 + tr;
    tile[i * 4 + tr][tc] = W1[(size_t)d * HID + by * 64 + tc];
  }
  __syncthreads();
  #pragma unroll
  for (int i = 0; i < 16; ++i) {
    const int n = by * 64 + i * 4 + tr;
    W1T[(size_t)n * TWOD + bx * 64 + tc] = f2bf(tile[tc][i * 4 + tr]);
  }
}

// 2048 blocks (2 per batch element), 512 threads = 8 waves, 128 rows per block.
// R12 equilibrium structure (64 arch VGPR + 64 AGPR acc = 4 waves/SIMD tier;
// kk-outer GEMM, 16 MFMAs per W1T fragment load) with:
//  - keys staged ONCE in LDS (coalesced) -> gather addresses come from LDS
//    broadcast reads, killing the per-pass serial key-load round.
//  - finalize fused via device-scope atomic completion counter (counter is
//    hipMemsetAsync'd to 0 every launch; ws is not re-poisoned by harness).
__global__ __launch_bounds__(512, 4) void nais_main(
    const int* __restrict__ history, const int* __restrict__ target,
    const int* __restrict__ hregion, const int* __restrict__ tregion,
    const float* __restrict__ E_hist, const float* __restrict__ E_targ,
    const float* __restrict__ E_reg,
    const unsigned short* __restrict__ W1T, const float* __restrict__ b1,
    const float* __restrict__ w2,
    float* __restrict__ part_se, float* __restrict__ part_sd,
    unsigned* __restrict__ counter, float* __restrict__ out)
{
  const int blk = blockIdx.x;
  const int b = blk >> 1;
  const int r0 = (blk & 1) * ROWS;      // row offset within the 256-history
  const int tid = threadIdx.x;
  const int lane = tid & 63;
  const int wave = tid >> 6;            // 0..7
  const int l15 = lane & 15;
  const int lhi = lane >> 4;
  const int l31 = lane & 31;
  const int halfsel = lane >> 5;        // 0: E_hist/E_targ half, 1: E_reg half

  __shared__ __align__(16) unsigned short inp_lds[ROWS * 256];  // 64 KiB, swizzled
  __shared__ float dot_lds[ROWS];
  __shared__ int keys_h[ROWS];
  __shared__ int keys_r[ROWS];
  __shared__ float score_parts[8][ROWS];
  __shared__ unsigned is_last;

  // per-lane target vector slice (4 floats), loaded directly (independent of bar)
  const float* tsrc = halfsel ? (E_reg + (size_t)tregion[b] * EMB)
                              : (E_targ + (size_t)target[b] * EMB);
  const f32x4 t = *(const f32x4*)(tsrc + l31 * 4);
  const int tgt_item = target[b];

  // ---- P0: stage keys coalesced (once per block, not per-lane) ----
  if (tid < ROWS) {
    keys_h[tid] = history[b * NH + r0 + tid];
  } else if (tid < 2 * ROWS) {
    keys_r[tid - ROWS] = hregion[b * NH + r0 + (tid - ROWS)];
  }
  __syncthreads();

  const float* table = halfsel ? E_reg : E_hist;
  const int* keys = halfsel ? keys_r : keys_h;

  // ---- P1: coalesced gather + multiply + bf16 tile + row sums ----
  #pragma unroll
  for (int pass = 0; pass < 2; ++pass) {
    int key8[8];
    #pragma unroll
    for (int s = 0; s < 8; ++s)
      key8[s] = keys[wave * 16 + pass * 8 + s];       // LDS broadcast read

    f32x4 vb[8];
    #pragma unroll
    for (int s = 0; s < 8; ++s)
      vb[s] = *(const f32x4*)(table + (size_t)key8[s] * EMB + l31 * 4);

    #pragma unroll
    for (int s = 0; s < 8; ++s) {
      const int row = wave * 16 + pass * 8 + s;
      f32x4 v = vb[s] * t;
      float ds = v[0] + v[1] + v[2] + v[3];
      ds += __shfl_xor(ds, 1);
      ds += __shfl_xor(ds, 2);
      ds += __shfl_xor(ds, 4);
      ds += __shfl_xor(ds, 8);
      ds += __shfl_xor(ds, 16);
      ds += __shfl_xor(ds, 32);         // combine E_hist + E_reg halves
      if (lane == 0) dot_lds[row] = ds;

      float2 f01; f01.x = v[0]; f01.y = v[1];
      float2 f23; f23.x = v[2]; f23.y = v[3];
      __hip_bfloat162 p0 = __float22bfloat162_rn(f01);
      __hip_bfloat162 p1 = __float22bfloat162_rn(f23);
      union { __hip_bfloat162 h; unsigned u; } c0, c1;
      c0.h = p0; c1.h = p1;
      const int g = halfsel * 16 + (l31 >> 1);          // 16B granule 0..31
      const int gs = g ^ (row & 7) ^ ((g >> 3) & 3);    // swizzle (bijective/row)
      unsigned* dst = (unsigned*)&inp_lds[row * 256 + gs * 8 + (lane & 1) * 4];
      dst[0] = c0.u; dst[1] = c1.u;
    }
  }
  __syncthreads();

  // ---- P2: GEMM. wave owns cols [wave*32, wave*32+32); kk outer,
  //      both 64-row chunks inner -> each bfr load feeds 16 MFMAs ----
  {
    const int col0 = wave * 32;
    float b1v[2], w2v[2];
    #pragma unroll
    for (int n = 0; n < 2; ++n) {
      const int colh = col0 + n * 16 + l15;
      b1v[n] = b1[colh];
      w2v[n] = w2[colh];
    }

    f32x4 acc[2][4][2];
    #pragma unroll
    for (int c = 0; c < 2; ++c)
      #pragma unroll
      for (int m = 0; m < 4; ++m)
        #pragma unroll
        for (int n = 0; n < 2; ++n)
          acc[c][m][n] = (f32x4){0.f, 0.f, 0.f, 0.f};

    #pragma unroll
    for (int kk = 0; kk < 8; ++kk) {
      bf16x8 bfr[2];
      #pragma unroll
      for (int n = 0; n < 2; ++n) {
        const int colh = col0 + n * 16 + l15;
        bfr[n] = *(const bf16x8*)(W1T + (size_t)colh * TWOD + kk * 32 + lhi * 8);
      }
      bf16x8 af[2][4];
      #pragma unroll
      for (int c = 0; c < 2; ++c)
        #pragma unroll
        for (int m = 0; m < 4; ++m) {
          const int row = c * 64 + m * 16 + l15;
          const int gk = kk * 4 + lhi;
          const int gs = gk ^ (row & 7) ^ ((gk >> 3) & 3);
          af[c][m] = *(const bf16x8*)(&inp_lds[row * 256 + gs * 8]);
        }
      __builtin_amdgcn_s_setprio(1);
      #pragma unroll
      for (int c = 0; c < 2; ++c)
        #pragma unroll
        for (int m = 0; m < 4; ++m)
          #pragma unroll
          for (int n = 0; n < 2; ++n)
            acc[c][m][n] = __builtin_amdgcn_mfma_f32_16x16x32_bf16(af[c][m], bfr[n], acc[c][m][n], 0, 0, 0);
      __builtin_amdgcn_s_setprio(0);
    }

    // epilogue: relu + b1, dot with w2, 16-lane reduce -> score_parts[wave][row]
    #pragma unroll
    for (int c = 0; c < 2; ++c) {
      #pragma unroll
      for (int m = 0; m < 4; ++m) {
        #pragma unroll
        for (int r = 0; r < 4; ++r) {
          float p = 0.f;
          #pragma unroll
          for (int n = 0; n < 2; ++n) {
            float hv = acc[c][m][n][r] + b1v[n];  // C/D: col=lane&15, row=(lane>>4)*4+r
            hv = hv > 0.f ? hv : 0.f;
            p += hv * w2v[n];
          }
          p += __shfl_xor(p, 1);
          p += __shfl_xor(p, 2);
          p += __shfl_xor(p, 4);
          p += __shfl_xor(p, 8);
          if (l15 == 0) score_parts[wave][c * 64 + m * 16 + lhi * 4 + r] = p;
        }
      }
    }
  }
  __syncthreads();

  // ---- P3: masked exp + partial sums -> per-(block,wave) ws slots ----
  if (wave < 2) {
    const int lrow = wave * 64 + lane;
    float sc = 0.f;
    #pragma unroll
    for (int w = 0; w < 8; ++w) sc += score_parts[w][lrow];
    float e = (keys_h[lrow] != tgt_item) ? expf(sc) : 0.f;
    float ed = e * dot_lds[lrow];
    #pragma unroll
    for (int off = 32; off >= 1; off >>= 1) {
      e += __shfl_xor(e, off);
      ed += __shfl_xor(ed, off);
    }
    if (lane == 0) {
      part_se[blk * 2 + wave] = e;   // layout: 4 contiguous slots per b
      part_sd[blk * 2 + wave] = ed;
    }
  }

  // ---- fused finalize: last-arriving block reduces all partials ----
  __threadfence();                     // each thread fences its own stores
  __syncthreads();
  if (tid == 0) {
    const unsigned old = atomicAdd(counter, 1u);
    is_last = (old == (unsigned)(NBLK - 1)) ? 1u : 0u;
  }
  __syncthreads();
  if (is_last) {
    __threadfence();                   // acquire: see all blocks' partials
    #pragma unroll
    for (int i = 0; i < 2; ++i) {
      const int bb = i * 512 + tid;    // 1024 b over 512 threads
      float se = 0.f, sd = 0.f;
      #pragma unroll
      for (int j = 0; j < BPB * 2; ++j) {
        se += part_se[bb * BPB * 2 + j];
        sd += part_sd[bb * BPB * 2 + j];
      }
      const float pred = (se > 0.f) ? (sd / sqrtf(se)) : 0.f;  // denom = sum^0.5
      out[bb] = 1.f / (1.f + expf(-pred));
    }
  }
}

extern "C" void kernel_launch(void* const* d_in, const int* in_sizes, int n_in,
                              void* d_out, int out_size, void* d_ws, size_t ws_size,
                              hipStream_t stream) {
  const int* history = (const int*)d_in[0];
  const int* target  = (const int*)d_in[1];
  const int* hregion = (const int*)d_in[2];
  const int* tregion = (const int*)d_in[3];
  const float* E_hist = (const float*)d_in[4];
  const float* E_targ = (const float*)d_in[5];
  const float* E_reg  = (const float*)d_in[6];
  const float* W1 = (const float*)d_in[7];
  const float* b1 = (const float*)d_in[8];
  const float* w2 = (const float*)d_in[9];
  float* out = (float*)d_out;

  char* p = (char*)d_ws;
  unsigned short* W1T = (unsigned short*)p;  p += (size_t)TWOD * HID * 2;   // 128 KB
  float* part_se = (float*)p;                p += (size_t)NBLK * 2 * 4;     // 16 KB
  float* part_sd = (float*)p;                p += (size_t)NBLK * 2 * 4;     // 16 KB
  unsigned* counter = (unsigned*)p;

  hipMemsetAsync(counter, 0, sizeof(unsigned), stream);
  prep_w1t<<<16, 256, 0, stream>>>(W1, W1T);
  nais_main<<<NBLK, 512, 0, stream>>>(history, target, hregion, tregion,
                                      E_hist, E_targ, E_reg, W1T, b1, w2,
                                      part_se, part_sd, counter, out);
}

// Round 14
// 87.480 us; speedup vs baseline: 3.6036x; 3.6036x over previous
//
#include <hip/hip_runtime.h>
#include <hip/hip_bf16.h>

#define NB 1024
#define NH 256
#define EMB 128
#define TWOD 256
#define HID 256
#define ROWS 128            // history rows per block
#define BPB 2               // blocks per batch element
#define NBLK (NB * BPB)

typedef __attribute__((ext_vector_type(4))) float f32x4;
typedef __attribute__((ext_vector_type(8))) short bf16x8;

__device__ __forceinline__ unsigned short f2bf(float f) {
  union { float f; unsigned u; } v; v.f = f;
  unsigned u = v.u;
  unsigned r = (u + 0x7fffu + ((u >> 16) & 1u)) >> 16;
  return (unsigned short)r;
}

// W1 [d=256][n=256] fp32 -> W1T [n][d] bf16, coalesced both sides via LDS
// tile transpose (16 blocks of 64x64 tiles).
__global__ __launch_bounds__(256) void prep_w1t(const float* __restrict__ W1,
                                                unsigned short* __restrict__ W1T) {
  const int bx = blockIdx.x & 3;        // d-tile
  const int by = blockIdx.x >> 2;       // n-tile
  __shared__ float tile[64][65];        // +1 pad: conflict-free transpose read
  const int tr = threadIdx.x >> 6;      // 0..3
  const int tc = threadIdx.x & 63;      // 0..63
  #pragma unroll
  for (int i = 0; i < 16; ++i) {
    const int d = bx * 64 + i * 4 + tr;
    tile[i * 4 + tr][tc] = W1[(size_t)d * HID + by * 64 + tc];
  }
  __syncthreads();
  #pragma unroll
  for (int i = 0; i < 16; ++i) {
    const int n = by * 64 + i * 4 + tr;
    W1T[(size_t)n * TWOD + bx * 64 + tc] = f2bf(tile[tc][i * 4 + tr]);
  }
}

// 2048 blocks (2 per batch element), 512 threads = 8 waves, 128 rows per block.
// EXACT round-12 structure (87.5us verified equilibrium: 64 arch VGPR +
// 64 AGPR acc = 4 waves/SIMD; kk-outer GEMM, 16 MFMAs per W1T fragment load;
// 2-pass gather, no scratch spill). R13 lesson: no device-scope fences or
// keys-LDS restructure on the per-block path.
__global__ __launch_bounds__(512, 4) void nais_main(
    const int* __restrict__ history, const int* __restrict__ target,
    const int* __restrict__ hregion, const int* __restrict__ tregion,
    const float* __restrict__ E_hist, const float* __restrict__ E_targ,
    const float* __restrict__ E_reg,
    const unsigned short* __restrict__ W1T, const float* __restrict__ b1,
    const float* __restrict__ w2,
    float* __restrict__ part_se, float* __restrict__ part_sd)
{
  const int blk = blockIdx.x;
  const int b = blk >> 1;
  const int r0 = (blk & 1) * ROWS;      // row offset within the 256-history
  const int tid = threadIdx.x;
  const int lane = tid & 63;
  const int wave = tid >> 6;            // 0..7
  const int l15 = lane & 15;
  const int lhi = lane >> 4;
  const int l31 = lane & 31;
  const int halfsel = lane >> 5;        // 0: E_hist/E_targ half, 1: E_reg half

  __shared__ __align__(16) unsigned short inp_lds[ROWS * 256];  // 64 KiB, swizzled
  __shared__ float dot_lds[ROWS];
  __shared__ int items_lds[ROWS];
  __shared__ float score_parts[8][ROWS];

  // per-lane target vector slice (4 floats), loaded directly
  const float* tsrc = halfsel ? (E_reg + (size_t)tregion[b] * EMB)
                              : (E_targ + (size_t)target[b] * EMB);
  const f32x4 t = *(const f32x4*)(tsrc + l31 * 4);
  const int tgt_item = target[b];

  const int* keysrc = halfsel ? hregion : history;
  const float* table = halfsel ? E_reg : E_hist;

  // ---- Phase 1: coalesced gather + multiply + bf16 tile + row sums ----
  {
    int key[16];
    #pragma unroll
    for (int s = 0; s < 16; ++s)
      key[s] = keysrc[b * NH + r0 + wave * 16 + s];

    #pragma unroll
    for (int pass = 0; pass < 2; ++pass) {
      f32x4 vb[8];
      #pragma unroll
      for (int s = 0; s < 8; ++s)
        vb[s] = *(const f32x4*)(table + (size_t)key[pass * 8 + s] * EMB + l31 * 4);

      #pragma unroll
      for (int s = 0; s < 8; ++s) {
        const int row = wave * 16 + pass * 8 + s;
        if (lane == 0) items_lds[row] = key[pass * 8 + s];  // lane 0: halfsel==0
        f32x4 v = vb[s] * t;
        float ds = v[0] + v[1] + v[2] + v[3];
        ds += __shfl_xor(ds, 1);
        ds += __shfl_xor(ds, 2);
        ds += __shfl_xor(ds, 4);
        ds += __shfl_xor(ds, 8);
        ds += __shfl_xor(ds, 16);
        ds += __shfl_xor(ds, 32);       // combine E_hist + E_reg halves
        if (lane == 0) dot_lds[row] = ds;

        float2 f01; f01.x = v[0]; f01.y = v[1];
        float2 f23; f23.x = v[2]; f23.y = v[3];
        __hip_bfloat162 p0 = __float22bfloat162_rn(f01);
        __hip_bfloat162 p1 = __float22bfloat162_rn(f23);
        union { __hip_bfloat162 h; unsigned u; } c0, c1;
        c0.h = p0; c1.h = p1;
        const int g = halfsel * 16 + (l31 >> 1);          // 16B granule 0..31
        const int gs = g ^ (row & 7) ^ ((g >> 3) & 3);    // swizzle (bijective/row)
        unsigned* dst = (unsigned*)&inp_lds[row * 256 + gs * 8 + (lane & 1) * 4];
        dst[0] = c0.u; dst[1] = c1.u;
      }
    }
  }
  __syncthreads();

  // ---- Phase 2: GEMM. wave owns cols [wave*32, wave*32+32); kk outer,
  //      both 64-row chunks inner -> each bfr load feeds 16 MFMAs ----
  {
    const int col0 = wave * 32;
    float b1v[2], w2v[2];
    #pragma unroll
    for (int n = 0; n < 2; ++n) {
      const int colh = col0 + n * 16 + l15;
      b1v[n] = b1[colh];
      w2v[n] = w2[colh];
    }

    f32x4 acc[2][4][2];
    #pragma unroll
    for (int c = 0; c < 2; ++c)
      #pragma unroll
      for (int m = 0; m < 4; ++m)
        #pragma unroll
        for (int n = 0; n < 2; ++n)
          acc[c][m][n] = (f32x4){0.f, 0.f, 0.f, 0.f};

    #pragma unroll
    for (int kk = 0; kk < 8; ++kk) {
      bf16x8 bfr[2];
      #pragma unroll
      for (int n = 0; n < 2; ++n) {
        const int colh = col0 + n * 16 + l15;
        bfr[n] = *(const bf16x8*)(W1T + (size_t)colh * TWOD + kk * 32 + lhi * 8);
      }
      bf16x8 af[2][4];
      #pragma unroll
      for (int c = 0; c < 2; ++c)
        #pragma unroll
        for (int m = 0; m < 4; ++m) {
          const int row = c * 64 + m * 16 + l15;
          const int gk = kk * 4 + lhi;
          const int gs = gk ^ (row & 7) ^ ((gk >> 3) & 3);
          af[c][m] = *(const bf16x8*)(&inp_lds[row * 256 + gs * 8]);
        }
      __builtin_amdgcn_s_setprio(1);
      #pragma unroll
      for (int c = 0; c < 2; ++c)
        #pragma unroll
        for (int m = 0; m < 4; ++m)
          #pragma unroll
          for (int n = 0; n < 2; ++n)
            acc[c][m][n] = __builtin_amdgcn_mfma_f32_16x16x32_bf16(af[c][m], bfr[n], acc[c][m][n], 0, 0, 0);
      __builtin_amdgcn_s_setprio(0);
    }

    // epilogue: relu + b1, dot with w2, 16-lane reduce -> score_parts[wave][row]
    #pragma unroll
    for (int c = 0; c < 2; ++c) {
      #pragma unroll
      for (int m = 0; m < 4; ++m) {
        #pragma unroll
        for (int r = 0; r < 4; ++r) {
          float p = 0.f;
          #pragma unroll
          for (int n = 0; n < 2; ++n) {
            float hv = acc[c][m][n][r] + b1v[n];  // C/D: col=lane&15, row=(lane>>4)*4+r
            hv = hv > 0.f ? hv : 0.f;
            p += hv * w2v[n];
          }
          p += __shfl_xor(p, 1);
          p += __shfl_xor(p, 2);
          p += __shfl_xor(p, 4);
          p += __shfl_xor(p, 8);
          if (l15 == 0) score_parts[wave][c * 64 + m * 16 + lhi * 4 + r] = p;
        }
      }
    }
  }
  __syncthreads();

  // ---- Phase 3: masked exp + partial sums -> per-(block,wave) ws slots ----
  if (wave < 2) {
    const int lrow = wave * 64 + lane;
    float sc = 0.f;
    #pragma unroll
    for (int w = 0; w < 8; ++w) sc += score_parts[w][lrow];
    float e = (items_lds[lrow] != tgt_item) ? expf(sc) : 0.f;
    float ed = e * dot_lds[lrow];
    #pragma unroll
    for (int off = 32; off >= 1; off >>= 1) {
      e += __shfl_xor(e, off);
      ed += __shfl_xor(ed, off);
    }
    if (lane == 0) {
      part_se[blk * 2 + wave] = e;
      part_sd[blk * 2 + wave] = ed;
    }
  }
}

__global__ __launch_bounds__(256) void finalize(const float* __restrict__ part_se,
                                                const float* __restrict__ part_sd,
                                                float* __restrict__ out) {
  const int b = blockIdx.x * 256 + threadIdx.x;
  if (b < NB) {
    float se = 0.f, sd = 0.f;
    #pragma unroll
    for (int i = 0; i < BPB * 2; ++i) {
      se += part_se[b * BPB * 2 + i];
      sd += part_sd[b * BPB * 2 + i];
    }
    const float pred = (se > 0.f) ? (sd / sqrtf(se)) : 0.f;  // denom = sum^0.5
    out[b] = 1.f / (1.f + expf(-pred));
  }
}

extern "C" void kernel_launch(void* const* d_in, const int* in_sizes, int n_in,
                              void* d_out, int out_size, void* d_ws, size_t ws_size,
                              hipStream_t stream) {
  const int* history = (const int*)d_in[0];
  const int* target  = (const int*)d_in[1];
  const int* hregion = (const int*)d_in[2];
  const int* tregion = (const int*)d_in[3];
  const float* E_hist = (const float*)d_in[4];
  const float* E_targ = (const float*)d_in[5];
  const float* E_reg  = (const float*)d_in[6];
  const float* W1 = (const float*)d_in[7];
  const float* b1 = (const float*)d_in[8];
  const float* w2 = (const float*)d_in[9];
  float* out = (float*)d_out;

  char* p = (char*)d_ws;
  unsigned short* W1T = (unsigned short*)p;  p += (size_t)TWOD * HID * 2;   // 128 KB
  float* part_se = (float*)p;                p += (size_t)NBLK * 2 * 4;     // 16 KB
  float* part_sd = (float*)p;

  prep_w1t<<<16, 256, 0, stream>>>(W1, W1T);
  nais_main<<<NBLK, 512, 0, stream>>>(history, target, hregion, tregion,
                                      E_hist, E_targ, E_reg, W1T, b1, w2,
                                      part_se, part_sd);
  finalize<<<(NB + 255) / 256, 256, 0, stream>>>(part_se, part_sd, out);
}